// Round 5
// baseline (300.974 us; speedup 1.0000x reference)
//
#include <hip/hip_runtime.h>

// ---------------------------------------------------------------------------
// Fused causal attention, MI355X gfx950.
// cast fp32->f16 -> QKV GEMM -> V transpose -> flash attention (strip-paired
// uniform blocks, dbuf gld16 K/V, operand-swap, no spills) -> out GEMM.
// MFMA 16x16x32 layouts (m89/m91/m120-verified):
//   A-frag: A[m=lane&15][k=(lane>>4)*8+j], j=0..7
//   B-frag: B[k=(lane>>4)*8+j][n=lane&15]
//   C/D   : row=(lane>>4)*4+reg, col=lane&15
// Attention swap: St = K*Q^T (C: row=key,col=q), O^T = V^T*P.
// R1: K/V LDS in fragment order (gld16 w/ per-lane pre-permuted global src).
// R2: P St->PV handoff in-register via permlane32/16_swap; setprio on MFMA.
// R3: attn XCD/bh-clustering swizzle; exp2-domain softmax; defer-max THR=0.
// R4: gemm frag-order LDS (0 conflicts) + XCD chunk swizzle (FETCH -20%);
//     1-deep pipeline with per-step vmcnt(0) REGRESSED (drain anti-pattern).
// R5: depth-2 ring pipeline (T3+T4 proper): 3 LDS buffers, counted vmcnt(4)
//     in steady state (tile t+1's loads stay in flight across the barrier),
//     stage(t+2) after the barrier. Loads get 2 full iterations to land.
// ---------------------------------------------------------------------------

typedef _Float16 f16x8 __attribute__((ext_vector_type(8)));
typedef float floatx4 __attribute__((ext_vector_type(4)));
typedef unsigned int uint2v __attribute__((ext_vector_type(2)));

union U4H8 { uint4 u; f16x8 h; };

__device__ __forceinline__ ushort f32_to_h_bits(float f) {
  _Float16 h = (_Float16)f;
  return __builtin_bit_cast(ushort, h);
}
__device__ __forceinline__ uint pack2h(float a, float b) {
  return (uint)f32_to_h_bits(a) | ((uint)f32_to_h_bits(b) << 16);
}
// bare 2^x (one v_exp_f32, no libm guards)
__device__ __forceinline__ float exp2_fast(float x) {
  float r;
  asm("v_exp_f32 %0, %1" : "=v"(r) : "v"(x));
  return r;
}

// async global->LDS, 16B/lane; LDS dest = wave-uniform base + lane*16
__device__ __forceinline__ void gld16(const void* g, void* l) {
  __builtin_amdgcn_global_load_lds(
      (const __attribute__((address_space(1))) unsigned char*)g,
      (__attribute__((address_space(3))) unsigned char*)l, 16, 0, 0);
}

// ---------------------------------------------------------------- cast kernel
__global__ __launch_bounds__(256) void cast_f32_f16(const float* __restrict__ in,
                                                    ushort* __restrict__ out) {
  int i = blockIdx.x * 256 + threadIdx.x;
  float4 v = ((const float4*)in)[i];
  ushort4 o;
  o.x = f32_to_h_bits(v.x);
  o.y = f32_to_h_bits(v.y);
  o.z = f32_to_h_bits(v.z);
  o.w = f32_to_h_bits(v.w);
  ((ushort4*)out)[i] = o;
}

// ------------------------------------------------------------------ GEMM B^T
// C[M,N] = A[M,K] * B[N,K]^T.  128x128 tile, BK=32, 4 waves 2x2, 4x4 MFMA.
// Depth-2 ring pipeline: 3 LDS buffers; per step: vmcnt(4) waits ONLY the
// oldest tile's 4 loads (next tile's stay in flight across the barrier),
// s_barrier, stage(t+2) into (t+2)%3 (barrier proved t-1's reads done),
// conflict-free frag reads, 16 MFMA. Last 2 steps drain with vmcnt(0).
// LDS fragment order: unit u=(half*4+mi): chunk u*512 + lane*8 holds
// A[m0+half*64+mi*16+(lane&15)][k0+(lane>>4)*8 ..+7]; B mirrors with n0.
template <int OUT_F16>
__global__ __launch_bounds__(256) void gemm_bt(const ushort* __restrict__ A,
                                               const ushort* __restrict__ B,
                                               void* __restrict__ Cv,
                                               int M, int N, int K) {
  __shared__ ushort As[3][4096];
  __shared__ ushort Bs[3][4096];

  const int tid = threadIdx.x;
  const int lane = tid & 63;
  const int w = tid >> 6;
  const int l15 = lane & 15;
  const int quad = lane >> 4;

  // bijective XCD chunk swizzle (requires gx*gy % 8 == 0): XCD k = lin&7
  // owns contiguous by-panels [8k, 8k+8) across all bx.
  const int gx = gridDim.x;
  const int lin = blockIdx.y * gx + blockIdx.x;
  const int qq = (gx * gridDim.y) >> 3;
  const int nl = (lin & 7) * qq + (lin >> 3);
  const int m0 = (nl / gx) * 128;
  const int n0 = (nl % gx) * 128;

  const int wm = (w & 1) * 64;
  const int wn = (w >> 1) * 64;

  floatx4 acc[4][4];
#pragma unroll
  for (int i = 0; i < 4; i++)
#pragma unroll
    for (int j = 0; j < 4; j++) acc[i][j] = (floatx4){0.f, 0.f, 0.f, 0.f};

  // staging source (fragment-order): wave w stages units (0,w) and (1,w)
  // of both A and B; lane l -> row (l&15), 16B chunk (l>>4).
  const int sr = lane & 15;
  const int sc = (lane >> 4) * 8;
  const ushort* Ap = A + (size_t)(m0 + w * 16 + sr) * K + sc;
  const ushort* Bp = B + (size_t)(n0 + w * 16 + sr) * K + sc;
  const size_t rstep = (size_t)64 * K;

  auto stage = [&](int k0, int buf) {
    gld16(Ap + k0, &As[buf][w * 512]);
    gld16(Ap + rstep + k0, &As[buf][(w + 4) * 512]);
    gld16(Bp + k0, &Bs[buf][w * 512]);
    gld16(Bp + rstep + k0, &Bs[buf][(w + 4) * 512]);
  };

  stage(0, 0);
  stage(32, 1);
  const int hA = (w & 1) * 4;   // this wave's A unit base (half = w&1)
  const int hB = (w >> 1) * 4;  // this wave's B unit base (half = w>>1)

  int bt = 0;   // buffer of tile t
  int bs = 2;   // buffer of tile t+2
  for (int k0 = 0; k0 < K; k0 += 32) {
    // steady state: 8 loads outstanding (tiles t, t+1); wait only tile t's 4.
    if (k0 + 64 < K) {
      asm volatile("s_waitcnt vmcnt(4)" ::: "memory");
    } else {
      asm volatile("s_waitcnt vmcnt(0)" ::: "memory");
    }
    __builtin_amdgcn_s_barrier();
    asm volatile("" ::: "memory");
    if (k0 + 64 < K) stage(k0 + 64, bs);

    U4H8 af[4], bf[4];
#pragma unroll
    for (int mi = 0; mi < 4; mi++)
      af[mi].u = *(const uint4*)&As[bt][(hA + mi) * 512 + lane * 8];
#pragma unroll
    for (int ni = 0; ni < 4; ni++)
      bf[ni].u = *(const uint4*)&Bs[bt][(hB + ni) * 512 + lane * 8];
#pragma unroll
    for (int mi = 0; mi < 4; mi++)
#pragma unroll
      for (int ni = 0; ni < 4; ni++)
        acc[mi][ni] = __builtin_amdgcn_mfma_f32_16x16x32_f16(af[mi].h, bf[ni].h,
                                                             acc[mi][ni], 0, 0, 0);
    bt = (bt == 2) ? 0 : bt + 1;
    bs = (bs == 2) ? 0 : bs + 1;
  }

#pragma unroll
  for (int mi = 0; mi < 4; mi++) {
#pragma unroll
    for (int r = 0; r < 4; r++) {
      size_t row = m0 + wm + mi * 16 + quad * 4 + r;
#pragma unroll
      for (int ni = 0; ni < 4; ni++) {
        size_t col = n0 + wn + ni * 16 + l15;
        float v = acc[mi][ni][r];
        if (OUT_F16)
          ((ushort*)Cv)[row * N + col] = f32_to_h_bits(v);
        else
          ((float*)Cv)[row * N + col] = v;
      }
    }
  }
}

// --------------------------------------------------------------- V transpose
// qkv [8192][3072] f16 -> vtg[bh=64][dh=64][key=2048] f16.
__global__ __launch_bounds__(256) void vtrans(const ushort* __restrict__ qkv,
                                              ushort* __restrict__ vtg) {
  __shared__ ushort T[64 * 66];
  const int tid = threadIdx.x;
  const int kt = blockIdx.x;
  const int bh = blockIdx.y;
  const int b = bh >> 4, h = bh & 15;

  const int r = tid >> 3;
  const int c = (tid & 7) * 8;
  const ushort* src = qkv + (size_t)(b * 2048 + kt * 64) * 3072 + 2048 + h * 64;
  uint4 v0 = *(const uint4*)(src + (size_t)r * 3072 + c);
  uint4 v1 = *(const uint4*)(src + (size_t)(r + 32) * 3072 + c);
  union { uint4 u; ushort s[8]; } a0, a1;
  a0.u = v0; a1.u = v1;
#pragma unroll
  for (int j = 0; j < 8; j++) {
    T[(c + j) * 66 + r] = a0.s[j];
    T[(c + j) * 66 + r + 32] = a1.s[j];
  }
  __syncthreads();

  const int d = tid >> 3;
  const int kc = (tid & 7) * 8;
  ushort* dst = vtg + (size_t)bh * 64 * 2048 + (size_t)kt * 64;
  union { uint u[4]; uint4 u4; } o0, o1;
#pragma unroll
  for (int i = 0; i < 4; i++) {
    o0.u[i] = *(const uint*)&T[d * 66 + kc + 2 * i];
    o1.u[i] = *(const uint*)&T[(d + 32) * 66 + kc + 2 * i];
  }
  *(uint4*)(dst + (size_t)d * 2048 + kc) = o0.u4;
  *(uint4*)(dst + (size_t)(d + 32) * 2048 + kc) = o1.u4;
}

// ------------------------------------------------------------ flash attention
// Block = strip pair (bx, 31-bx), each strip 64 q; wave w owns q granules.
// 1-D grid 1024; decode: xcd=id&7, n=id>>3, bx=n>>3, bh=xcd*8+(n&7) so each
// XCD works on 8 bh (K/V ~4MB, L2-resident) across all 16 bx.
// K/V double-buffered via gld16; LDS fragment order (sub*64+lane chunks).
__global__ __launch_bounds__(256, 4) void attn_fused(const ushort* __restrict__ qkv,
                                                     const ushort* __restrict__ vtg,
                                                     ushort* __restrict__ attn_out) {
  __shared__ ushort Ks[2][4096];        // [buf][(t*2+kc)*512 + lane*8]  16 KB
  __shared__ ushort Vs[2][4096];        // [buf][(ni*2+kc)*512 + lane*8] 16 KB
  __shared__ ushort Ps[4][16 * 40];     // per-wave epilogue transpose    5 KB

  const int tid = threadIdx.x;
  const int lane = tid & 63;
  const int w = tid >> 6;
  const int l15 = lane & 15;
  const int quad = lane >> 4;
  const int id = blockIdx.x;            // 0..1023
  const int n_ = id >> 3;
  const int bx = n_ >> 3;               // 0..15
  const int bh = (id & 7) * 8 + (n_ & 7);
  const int b = bh >> 4;
  const int h = bh & 15;
  const int bS = b * 2048;
  const int qtA = bx;
  const int qtB = 31 - bx;
  const int ktmax = qtB;
  int q0s[2];
  q0s[0] = qtA * 64 + w * 16;
  q0s[1] = qtB * 64 + w * 16;

  // Q B-frags (B[k=dh][n=q] == Q[q][dh]), pre-scaled by log2(e)/sqrt(64)
  // (exp2-domain softmax: S2 = S * log2e, p = 2^(S2 - m2)).
  U4H8 qf[2][2];
#pragma unroll
  for (int s = 0; s < 2; s++) {
    const ushort* qrow = qkv + (size_t)(bS + q0s[s] + l15) * 3072 + h * 64;
#pragma unroll
    for (int kc = 0; kc < 2; kc++) {
      qf[s][kc].u = *(const uint4*)(qrow + kc * 32 + quad * 8);
      qf[s][kc].h = qf[s][kc].h * (_Float16)0.1803368787f;  // 0.125*log2(e)
    }
  }

  floatx4 o[2][4];  // [strip][dh tile]; D: dh=ni*16+quad*4+r, q=l15
#pragma unroll
  for (int s = 0; s < 2; s++)
#pragma unroll
    for (int ni = 0; ni < 4; ni++) o[s][ni] = (floatx4){0.f, 0.f, 0.f, 0.f};
  float m_i[2] = {-1e30f, -1e30f}, l_i[2] = {0.f, 0.f};

  const ushort* kbase = qkv + (size_t)bS * 3072 + 1024 + h * 64;
  const ushort* vbase = vtg + (size_t)bh * 64 * 2048;
  const int sr = lane & 15;          // source row within 16-row granule
  const int scc = (lane >> 4) * 8;   // source 8-ushort chunk within 32

  // wave w stages key granule t=w of K and dh granule ni=w of V, in exact
  // fragment-read order (lane l -> row l&15, chunk l>>4).
  auto stage = [&](int kt, int buf) {
    const ushort* kg = kbase + (size_t)(kt * 64 + w * 16 + sr) * 3072 + scc;
    gld16(kg, &Ks[buf][(w * 2 + 0) * 512]);
    gld16(kg + 32, &Ks[buf][(w * 2 + 1) * 512]);
    const ushort* vg = vbase + (size_t)(w * 16 + sr) * 2048 + (size_t)kt * 64 + scc;
    gld16(vg, &Vs[buf][(w * 2 + 0) * 512]);
    gld16(vg + 32, &Vs[buf][(w * 2 + 1) * 512]);
  };

  auto strip_step = [&](int s, bool diag, int kt64, int buf) {
    // ---- St = K Q^T  (all 4 subtiles; diagonal handled by mask)
    floatx4 s4[4];
    __builtin_amdgcn_s_setprio(1);
#pragma unroll
    for (int t = 0; t < 4; t++) {
      U4H8 kf0, kf1;
      kf0.u = *(const uint4*)&Ks[buf][(t * 2 + 0) * 512 + lane * 8];
      kf1.u = *(const uint4*)&Ks[buf][(t * 2 + 1) * 512 + lane * 8];
      floatx4 sa = (floatx4){0.f, 0.f, 0.f, 0.f};
      sa = __builtin_amdgcn_mfma_f32_16x16x32_f16(kf0.h, qf[s][0].h, sa, 0, 0, 0);
      sa = __builtin_amdgcn_mfma_f32_16x16x32_f16(kf1.h, qf[s][1].h, sa, 0, 0, 0);
      s4[t] = sa;
    }
    __builtin_amdgcn_s_setprio(0);
    if (diag) {
      const int q = q0s[s] + l15;
#pragma unroll
      for (int t = 0; t < 4; t++)
#pragma unroll
        for (int r = 0; r < 4; r++) {
          int key = kt64 + t * 16 + quad * 4 + r;
          if (key > q) s4[t][r] = -1e30f;
        }
    }

    // ---- online softmax, exp2 domain (16 in-lane keys + quads via shfl)
    float tmax = -1e30f;
#pragma unroll
    for (int t = 0; t < 4; t++)
#pragma unroll
      for (int r = 0; r < 4; r++) tmax = fmaxf(tmax, s4[t][r]);
    tmax = fmaxf(tmax, __shfl_xor(tmax, 16));
    tmax = fmaxf(tmax, __shfl_xor(tmax, 32));
    // defer-max THR=0: rescale only if some lane's max grew (alpha==1 else).
    if (__any(tmax > m_i[s])) {
      float mnew = fmaxf(m_i[s], tmax);
      float alpha = exp2_fast(m_i[s] - mnew);
      m_i[s] = mnew;
      l_i[s] *= alpha;
#pragma unroll
      for (int ni = 0; ni < 4; ni++) o[s][ni] *= alpha;
    }
    const float m2 = m_i[s];
    float rs = 0.f;
#pragma unroll
    for (int t = 0; t < 4; t++)
#pragma unroll
      for (int r = 0; r < 4; r++) {
        float p = exp2_fast(s4[t][r] - m2);
        s4[t][r] = p;
        rs += p;
      }
    rs += __shfl_xor(rs, 16);
    rs += __shfl_xor(rs, 32);
    l_i[s] += rs;

    // ---- O^T += V^T P; P B-frag built in-register via permlane swaps.
    // St C-layout: lane(quad_s,l15) holds key=t*16+quad_s*4+r, q=l15.
    // PV B-frag:  lane(quad_d,l15) needs key=kc*32+quad_d*8+j, q=l15.
#pragma unroll
    for (int kc = 0; kc < 2; kc++) {
      uint pA = pack2h(s4[kc * 2][0], s4[kc * 2][1]);
      uint pB = pack2h(s4[kc * 2][2], s4[kc * 2][3]);
      uint pC = pack2h(s4[kc * 2 + 1][0], s4[kc * 2 + 1][1]);
      uint pD = pack2h(s4[kc * 2 + 1][2], s4[kc * 2 + 1][3]);
      uint2v ac = __builtin_amdgcn_permlane32_swap(pA, pC, false, false);
      uint2v bd = __builtin_amdgcn_permlane32_swap(pB, pD, false, false);
      uint2v ac2 = __builtin_amdgcn_permlane16_swap(ac[0], ac[1], false, false);
      uint2v bd2 = __builtin_amdgcn_permlane16_swap(bd[0], bd[1], false, false);
      U4H8 pb;
      pb.u = (uint4){ac2[0], bd2[0], ac2[1], bd2[1]};  // j01,j23,j45,j67
      __builtin_amdgcn_s_setprio(1);
#pragma unroll
      for (int ni = 0; ni < 4; ni++) {
        U4H8 vf;
        vf.u = *(const uint4*)&Vs[buf][(ni * 2 + kc) * 512 + lane * 8];
        o[s][ni] = __builtin_amdgcn_mfma_f32_16x16x32_f16(vf.h, pb.h, o[s][ni], 0, 0, 0);
      }
      __builtin_amdgcn_s_setprio(0);
    }
  };

  stage(0, 0);
  for (int kt = 0; kt <= ktmax; ++kt) {
    const int buf = kt & 1;
    __syncthreads();  // drains vmcnt -> buf staged; prior LDS reads done
    if (kt < ktmax) stage(kt + 1, buf ^ 1);
    strip_step(1, kt == qtB, kt * 64, buf);
    if (kt <= qtA) strip_step(0, kt == qtA, kt * 64, buf);
  }

  // ---- epilogue: O^T -> transpose via Ps (two 32-col passes) -> coalesced
#pragma unroll
  for (int s = 0; s < 2; s++) {
    float inv = 1.0f / l_i[s];
    ushort* orow = attn_out + (size_t)(bS + q0s[s] + l15) * 1024 + h * 64;
#pragma unroll
    for (int p = 0; p < 2; p++) {
#pragma unroll
      for (int nh = 0; nh < 2; nh++) {
        const int ni = p * 2 + nh;
        *(uint*)&Ps[w][l15 * 40 + nh * 16 + quad * 4] =
            pack2h(o[s][ni][0] * inv, o[s][ni][1] * inv);
        *(uint*)&Ps[w][l15 * 40 + nh * 16 + quad * 4 + 2] =
            pack2h(o[s][ni][2] * inv, o[s][ni][3] * inv);
      }
      __asm__ volatile("s_waitcnt lgkmcnt(0)" ::: "memory");
      uint4 x = *(const uint4*)&Ps[w][l15 * 40 + quad * 8];
      *(uint4*)(orow + p * 32 + quad * 8) = x;
      __asm__ volatile("s_waitcnt lgkmcnt(0)" ::: "memory");  // reads before reuse
    }
  }
}

// ---------------------------------------------------------------------- launch
extern "C" void kernel_launch(void* const* d_in, const int* in_sizes, int n_in,
                              void* d_out, int out_size, void* d_ws, size_t ws_size,
                              hipStream_t stream) {
  const float* x = (const float*)d_in[0];       // [4,2048,1024]
  const float* wqkv = (const float*)d_in[1];    // [3072,1024]
  const float* wo = (const float*)d_in[2];      // [1024,1024]
  float* out = (float*)d_out;                   // [4,2048,1024] fp32

  ushort* xh = (ushort*)d_ws;                          // 8192*1024
  ushort* wqkvh = xh + (size_t)8192 * 1024;            // 3072*1024
  ushort* woh = wqkvh + (size_t)3072 * 1024;           // 1024*1024
  ushort* qkvh = woh + (size_t)1024 * 1024;            // 8192*3072
  ushort* attnh = qkvh + (size_t)8192 * 3072;          // 8192*1024
  ushort* vtg = attnh + (size_t)8192 * 1024;           // 64*64*2048
  // total ws use: ~109 MB

  cast_f32_f16<<<8192, 256, 0, stream>>>(x, xh);
  cast_f32_f16<<<3072, 256, 0, stream>>>(wqkv, wqkvh);
  cast_f32_f16<<<1024, 256, 0, stream>>>(wo, woh);

  gemm_bt<1><<<dim3(24, 64), 256, 0, stream>>>(xh, wqkvh, qkvh, 8192, 3072, 1024);
  vtrans<<<dim3(32, 64), 256, 0, stream>>>(qkvh, vtg);
  attn_fused<<<dim3(1024), 256, 0, stream>>>(qkvh, vtg, attnh);
  gemm_bt<0><<<dim3(8, 64), 256, 0, stream>>>(attnh, woh, out, 8192, 1024, 1024);
}

// Round 6
// 257.225 us; speedup vs baseline: 1.1701x; 1.1701x over previous
//
#include <hip/hip_runtime.h>

// ---------------------------------------------------------------------------
// Fused causal attention, MI355X gfx950.
// cast fp32->f16 -> QKV GEMM -> V transpose -> flash attention (strip-paired
// uniform blocks, dbuf gld16 K/V, operand-swap, no spills) -> out GEMM.
// MFMA 16x16x32 layouts (m89/m91/m120-verified):
//   A-frag: A[m=lane&15][k=(lane>>4)*8+j], j=0..7
//   B-frag: B[k=(lane>>4)*8+j][n=lane&15]
//   C/D   : row=(lane>>4)*4+reg, col=lane&15
// Attention swap: St = K*Q^T (C: row=key,col=q), O^T = V^T*P.
// R1: K/V LDS in fragment order (gld16 w/ per-lane pre-permuted global src).
// R2: P St->PV handoff in-register via permlane32/16_swap; setprio on MFMA.
// R3: attn XCD/bh-clustering swizzle; exp2-domain softmax; defer-max THR=0.
// R4/R5: ring pipeline + frag-order staging REGRESSED: lane map l&15 broke
//     adjacent-lane 64B-line merging -> 4x VMEM request count, fetch-rate
//     capped ~550 GB/s, both GEMMs pinned at 107us regardless of FLOPs.
// R6: line-merged staging RESTORED (lane l -> row l>>2; 4 lanes = one 64B
//     line) + chunk-XOR swizzle on the GLOBAL SOURCE (chunk = (l&3)^((l>>3)&3),
//     LDS linear row-major) and matching XOR on reads (quad ^ ((l15>>1)&3)):
//     coalescing of R3 + even all-bank ds_read_b128 distribution. Ring
//     pipeline (3 buf, vmcnt(4)) and XCD chunk swizzle kept.
// ---------------------------------------------------------------------------

typedef _Float16 f16x8 __attribute__((ext_vector_type(8)));
typedef float floatx4 __attribute__((ext_vector_type(4)));
typedef unsigned int uint2v __attribute__((ext_vector_type(2)));

union U4H8 { uint4 u; f16x8 h; };

__device__ __forceinline__ ushort f32_to_h_bits(float f) {
  _Float16 h = (_Float16)f;
  return __builtin_bit_cast(ushort, h);
}
__device__ __forceinline__ uint pack2h(float a, float b) {
  return (uint)f32_to_h_bits(a) | ((uint)f32_to_h_bits(b) << 16);
}
// bare 2^x (one v_exp_f32, no libm guards)
__device__ __forceinline__ float exp2_fast(float x) {
  float r;
  asm("v_exp_f32 %0, %1" : "=v"(r) : "v"(x));
  return r;
}

// async global->LDS, 16B/lane; LDS dest = wave-uniform base + lane*16
__device__ __forceinline__ void gld16(const void* g, void* l) {
  __builtin_amdgcn_global_load_lds(
      (const __attribute__((address_space(1))) unsigned char*)g,
      (__attribute__((address_space(3))) unsigned char*)l, 16, 0, 0);
}

// ---------------------------------------------------------------- cast kernel
__global__ __launch_bounds__(256) void cast_f32_f16(const float* __restrict__ in,
                                                    ushort* __restrict__ out) {
  int i = blockIdx.x * 256 + threadIdx.x;
  float4 v = ((const float4*)in)[i];
  ushort4 o;
  o.x = f32_to_h_bits(v.x);
  o.y = f32_to_h_bits(v.y);
  o.z = f32_to_h_bits(v.z);
  o.w = f32_to_h_bits(v.w);
  ((ushort4*)out)[i] = o;
}

// ------------------------------------------------------------------ GEMM B^T
// C[M,N] = A[M,K] * B[N,K]^T.  128x128 tile, BK=32, 4 waves 2x2, 4x4 MFMA.
// Depth-2 ring pipeline: 3 LDS buffers; per step: vmcnt(4) waits ONLY the
// oldest tile's loads, s_barrier, stage(t+2), frag reads, 16 MFMA.
// Staging (line-merged + source-swizzled): lane l loads
//   A[m0 + w*16 + (l>>2)][16B-chunk (l&3)^((l>>3)&3)]
// into linear LDS slot lane*16 -> LDS holds row-major [row][32] with
// physical chunk p containing logical chunk p^((row>>1)&3).
// Reads: logical chunk quad at row R -> physical quad^((R>>1)&3), R%16=l15.
template <int OUT_F16>
__global__ __launch_bounds__(256) void gemm_bt(const ushort* __restrict__ A,
                                               const ushort* __restrict__ B,
                                               void* __restrict__ Cv,
                                               int M, int N, int K) {
  __shared__ ushort As[3][4096];
  __shared__ ushort Bs[3][4096];

  const int tid = threadIdx.x;
  const int lane = tid & 63;
  const int w = tid >> 6;
  const int l15 = lane & 15;
  const int quad = lane >> 4;

  // bijective XCD chunk swizzle (requires gx*gy % 8 == 0): XCD k = lin&7
  // owns contiguous by-panels [8k, 8k+8) across all bx.
  const int gx = gridDim.x;
  const int lin = blockIdx.y * gx + blockIdx.x;
  const int qq = (gx * gridDim.y) >> 3;
  const int nl = (lin & 7) * qq + (lin >> 3);
  const int m0 = (nl / gx) * 128;
  const int n0 = (nl % gx) * 128;

  const int wm = (w & 1) * 64;
  const int wn = (w >> 1) * 64;

  floatx4 acc[4][4];
#pragma unroll
  for (int i = 0; i < 4; i++)
#pragma unroll
    for (int j = 0; j < 4; j++) acc[i][j] = (floatx4){0.f, 0.f, 0.f, 0.f};

  // staging source: row w*16 + (l>>2) (4 adjacent lanes share one 64B line),
  // chunk XOR-swizzled so linear LDS dest yields the swizzled layout.
  const int srow = w * 16 + (lane >> 2);
  const int sq = ((lane & 3) ^ ((lane >> 3) & 3)) * 8;
  const ushort* Ap = A + (size_t)(m0 + srow) * K + sq;
  const ushort* Bp = B + (size_t)(n0 + srow) * K + sq;
  const size_t rstep = (size_t)64 * K;

  auto stage = [&](int k0, int buf) {
    gld16(Ap + k0, &As[buf][w * 512]);
    gld16(Ap + rstep + k0, &As[buf][(w + 4) * 512]);
    gld16(Bp + k0, &Bs[buf][w * 512]);
    gld16(Bp + rstep + k0, &Bs[buf][(w + 4) * 512]);
  };

  stage(0, 0);
  stage(32, 1);

  const int psw = (quad ^ ((l15 >> 1) & 3)) * 8;  // physical chunk for reads

  int bt = 0;   // buffer of tile t
  int bs = 2;   // buffer of tile t+2
  for (int k0 = 0; k0 < K; k0 += 32) {
    // steady state: 8 loads outstanding (tiles t, t+1); wait only tile t's 4.
    if (k0 + 64 < K) {
      asm volatile("s_waitcnt vmcnt(4)" ::: "memory");
    } else {
      asm volatile("s_waitcnt vmcnt(0)" ::: "memory");
    }
    __builtin_amdgcn_s_barrier();
    asm volatile("" ::: "memory");
    if (k0 + 64 < K) stage(k0 + 64, bs);

    U4H8 af[4], bf[4];
#pragma unroll
    for (int mi = 0; mi < 4; mi++)
      af[mi].u = *(const uint4*)&As[bt][(wm + mi * 16 + l15) * 32 + psw];
#pragma unroll
    for (int ni = 0; ni < 4; ni++)
      bf[ni].u = *(const uint4*)&Bs[bt][(wn + ni * 16 + l15) * 32 + psw];
#pragma unroll
    for (int mi = 0; mi < 4; mi++)
#pragma unroll
      for (int ni = 0; ni < 4; ni++)
        acc[mi][ni] = __builtin_amdgcn_mfma_f32_16x16x32_f16(af[mi].h, bf[ni].h,
                                                             acc[mi][ni], 0, 0, 0);
    bt = (bt == 2) ? 0 : bt + 1;
    bs = (bs == 2) ? 0 : bs + 1;
  }

#pragma unroll
  for (int mi = 0; mi < 4; mi++) {
#pragma unroll
    for (int r = 0; r < 4; r++) {
      size_t row = m0 + wm + mi * 16 + quad * 4 + r;
#pragma unroll
      for (int ni = 0; ni < 4; ni++) {
        size_t col = n0 + wn + ni * 16 + l15;
        float v = acc[mi][ni][r];
        if (OUT_F16)
          ((ushort*)Cv)[row * N + col] = f32_to_h_bits(v);
        else
          ((float*)Cv)[row * N + col] = v;
      }
    }
  }
}

// --------------------------------------------------------------- V transpose
// qkv [8192][3072] f16 -> vtg[bh=64][dh=64][key=2048] f16.
__global__ __launch_bounds__(256) void vtrans(const ushort* __restrict__ qkv,
                                              ushort* __restrict__ vtg) {
  __shared__ ushort T[64 * 66];
  const int tid = threadIdx.x;
  const int kt = blockIdx.x;
  const int bh = blockIdx.y;
  const int b = bh >> 4, h = bh & 15;

  const int r = tid >> 3;
  const int c = (tid & 7) * 8;
  const ushort* src = qkv + (size_t)(b * 2048 + kt * 64) * 3072 + 2048 + h * 64;
  uint4 v0 = *(const uint4*)(src + (size_t)r * 3072 + c);
  uint4 v1 = *(const uint4*)(src + (size_t)(r + 32) * 3072 + c);
  union { uint4 u; ushort s[8]; } a0, a1;
  a0.u = v0; a1.u = v1;
#pragma unroll
  for (int j = 0; j < 8; j++) {
    T[(c + j) * 66 + r] = a0.s[j];
    T[(c + j) * 66 + r + 32] = a1.s[j];
  }
  __syncthreads();

  const int d = tid >> 3;
  const int kc = (tid & 7) * 8;
  ushort* dst = vtg + (size_t)bh * 64 * 2048 + (size_t)kt * 64;
  union { uint u[4]; uint4 u4; } o0, o1;
#pragma unroll
  for (int i = 0; i < 4; i++) {
    o0.u[i] = *(const uint*)&T[d * 66 + kc + 2 * i];
    o1.u[i] = *(const uint*)&T[(d + 32) * 66 + kc + 2 * i];
  }
  *(uint4*)(dst + (size_t)d * 2048 + kc) = o0.u4;
  *(uint4*)(dst + (size_t)(d + 32) * 2048 + kc) = o1.u4;
}

// ------------------------------------------------------------ flash attention
// Block = strip pair (bx, 31-bx), each strip 64 q; wave w owns q granules.
// 1-D grid 1024; decode: xcd=id&7, n=id>>3, bx=n>>3, bh=xcd*8+(n&7) so each
// XCD works on 8 bh (K/V ~4MB, L2-resident) across all 16 bx.
// K/V double-buffered via gld16; LDS fragment order (sub*64+lane chunks).
__global__ __launch_bounds__(256, 4) void attn_fused(const ushort* __restrict__ qkv,
                                                     const ushort* __restrict__ vtg,
                                                     ushort* __restrict__ attn_out) {
  __shared__ ushort Ks[2][4096];        // [buf][(t*2+kc)*512 + lane*8]  16 KB
  __shared__ ushort Vs[2][4096];        // [buf][(ni*2+kc)*512 + lane*8] 16 KB
  __shared__ ushort Ps[4][16 * 40];     // per-wave epilogue transpose    5 KB

  const int tid = threadIdx.x;
  const int lane = tid & 63;
  const int w = tid >> 6;
  const int l15 = lane & 15;
  const int quad = lane >> 4;
  const int id = blockIdx.x;            // 0..1023
  const int n_ = id >> 3;
  const int bx = n_ >> 3;               // 0..15
  const int bh = (id & 7) * 8 + (n_ & 7);
  const int b = bh >> 4;
  const int h = bh & 15;
  const int bS = b * 2048;
  const int qtA = bx;
  const int qtB = 31 - bx;
  const int ktmax = qtB;
  int q0s[2];
  q0s[0] = qtA * 64 + w * 16;
  q0s[1] = qtB * 64 + w * 16;

  // Q B-frags (B[k=dh][n=q] == Q[q][dh]), pre-scaled by log2(e)/sqrt(64)
  // (exp2-domain softmax: S2 = S * log2e, p = 2^(S2 - m2)).
  U4H8 qf[2][2];
#pragma unroll
  for (int s = 0; s < 2; s++) {
    const ushort* qrow = qkv + (size_t)(bS + q0s[s] + l15) * 3072 + h * 64;
#pragma unroll
    for (int kc = 0; kc < 2; kc++) {
      qf[s][kc].u = *(const uint4*)(qrow + kc * 32 + quad * 8);
      qf[s][kc].h = qf[s][kc].h * (_Float16)0.1803368787f;  // 0.125*log2(e)
    }
  }

  floatx4 o[2][4];  // [strip][dh tile]; D: dh=ni*16+quad*4+r, q=l15
#pragma unroll
  for (int s = 0; s < 2; s++)
#pragma unroll
    for (int ni = 0; ni < 4; ni++) o[s][ni] = (floatx4){0.f, 0.f, 0.f, 0.f};
  float m_i[2] = {-1e30f, -1e30f}, l_i[2] = {0.f, 0.f};

  const ushort* kbase = qkv + (size_t)bS * 3072 + 1024 + h * 64;
  const ushort* vbase = vtg + (size_t)bh * 64 * 2048;
  const int sr = lane & 15;          // source row within 16-row granule
  const int scc = (lane >> 4) * 8;   // source 8-ushort chunk within 32

  // wave w stages key granule t=w of K and dh granule ni=w of V, in exact
  // fragment-read order (lane l -> row l&15, chunk l>>4).
  auto stage = [&](int kt, int buf) {
    const ushort* kg = kbase + (size_t)(kt * 64 + w * 16 + sr) * 3072 + scc;
    gld16(kg, &Ks[buf][(w * 2 + 0) * 512]);
    gld16(kg + 32, &Ks[buf][(w * 2 + 1) * 512]);
    const ushort* vg = vbase + (size_t)(w * 16 + sr) * 2048 + (size_t)kt * 64 + scc;
    gld16(vg, &Vs[buf][(w * 2 + 0) * 512]);
    gld16(vg + 32, &Vs[buf][(w * 2 + 1) * 512]);
  };

  auto strip_step = [&](int s, bool diag, int kt64, int buf) {
    // ---- St = K Q^T  (all 4 subtiles; diagonal handled by mask)
    floatx4 s4[4];
    __builtin_amdgcn_s_setprio(1);
#pragma unroll
    for (int t = 0; t < 4; t++) {
      U4H8 kf0, kf1;
      kf0.u = *(const uint4*)&Ks[buf][(t * 2 + 0) * 512 + lane * 8];
      kf1.u = *(const uint4*)&Ks[buf][(t * 2 + 1) * 512 + lane * 8];
      floatx4 sa = (floatx4){0.f, 0.f, 0.f, 0.f};
      sa = __builtin_amdgcn_mfma_f32_16x16x32_f16(kf0.h, qf[s][0].h, sa, 0, 0, 0);
      sa = __builtin_amdgcn_mfma_f32_16x16x32_f16(kf1.h, qf[s][1].h, sa, 0, 0, 0);
      s4[t] = sa;
    }
    __builtin_amdgcn_s_setprio(0);
    if (diag) {
      const int q = q0s[s] + l15;
#pragma unroll
      for (int t = 0; t < 4; t++)
#pragma unroll
        for (int r = 0; r < 4; r++) {
          int key = kt64 + t * 16 + quad * 4 + r;
          if (key > q) s4[t][r] = -1e30f;
        }
    }

    // ---- online softmax, exp2 domain (16 in-lane keys + quads via shfl)
    float tmax = -1e30f;
#pragma unroll
    for (int t = 0; t < 4; t++)
#pragma unroll
      for (int r = 0; r < 4; r++) tmax = fmaxf(tmax, s4[t][r]);
    tmax = fmaxf(tmax, __shfl_xor(tmax, 16));
    tmax = fmaxf(tmax, __shfl_xor(tmax, 32));
    // defer-max THR=0: rescale only if some lane's max grew (alpha==1 else).
    if (__any(tmax > m_i[s])) {
      float mnew = fmaxf(m_i[s], tmax);
      float alpha = exp2_fast(m_i[s] - mnew);
      m_i[s] = mnew;
      l_i[s] *= alpha;
#pragma unroll
      for (int ni = 0; ni < 4; ni++) o[s][ni] *= alpha;
    }
    const float m2 = m_i[s];
    float rs = 0.f;
#pragma unroll
    for (int t = 0; t < 4; t++)
#pragma unroll
      for (int r = 0; r < 4; r++) {
        float p = exp2_fast(s4[t][r] - m2);
        s4[t][r] = p;
        rs += p;
      }
    rs += __shfl_xor(rs, 16);
    rs += __shfl_xor(rs, 32);
    l_i[s] += rs;

    // ---- O^T += V^T P; P B-frag built in-register via permlane swaps.
    // St C-layout: lane(quad_s,l15) holds key=t*16+quad_s*4+r, q=l15.
    // PV B-frag:  lane(quad_d,l15) needs key=kc*32+quad_d*8+j, q=l15.
#pragma unroll
    for (int kc = 0; kc < 2; kc++) {
      uint pA = pack2h(s4[kc * 2][0], s4[kc * 2][1]);
      uint pB = pack2h(s4[kc * 2][2], s4[kc * 2][3]);
      uint pC = pack2h(s4[kc * 2 + 1][0], s4[kc * 2 + 1][1]);
      uint pD = pack2h(s4[kc * 2 + 1][2], s4[kc * 2 + 1][3]);
      uint2v ac = __builtin_amdgcn_permlane32_swap(pA, pC, false, false);
      uint2v bd = __builtin_amdgcn_permlane32_swap(pB, pD, false, false);
      uint2v ac2 = __builtin_amdgcn_permlane16_swap(ac[0], ac[1], false, false);
      uint2v bd2 = __builtin_amdgcn_permlane16_swap(bd[0], bd[1], false, false);
      U4H8 pb;
      pb.u = (uint4){ac2[0], bd2[0], ac2[1], bd2[1]};  // j01,j23,j45,j67
      __builtin_amdgcn_s_setprio(1);
#pragma unroll
      for (int ni = 0; ni < 4; ni++) {
        U4H8 vf;
        vf.u = *(const uint4*)&Vs[buf][(ni * 2 + kc) * 512 + lane * 8];
        o[s][ni] = __builtin_amdgcn_mfma_f32_16x16x32_f16(vf.h, pb.h, o[s][ni], 0, 0, 0);
      }
      __builtin_amdgcn_s_setprio(0);
    }
  };

  stage(0, 0);
  for (int kt = 0; kt <= ktmax; ++kt) {
    const int buf = kt & 1;
    __syncthreads();  // drains vmcnt -> buf staged; prior LDS reads done
    if (kt < ktmax) stage(kt + 1, buf ^ 1);
    strip_step(1, kt == qtB, kt * 64, buf);
    if (kt <= qtA) strip_step(0, kt == qtA, kt * 64, buf);
  }

  // ---- epilogue: O^T -> transpose via Ps (two 32-col passes) -> coalesced
#pragma unroll
  for (int s = 0; s < 2; s++) {
    float inv = 1.0f / l_i[s];
    ushort* orow = attn_out + (size_t)(bS + q0s[s] + l15) * 1024 + h * 64;
#pragma unroll
    for (int p = 0; p < 2; p++) {
#pragma unroll
      for (int nh = 0; nh < 2; nh++) {
        const int ni = p * 2 + nh;
        *(uint*)&Ps[w][l15 * 40 + nh * 16 + quad * 4] =
            pack2h(o[s][ni][0] * inv, o[s][ni][1] * inv);
        *(uint*)&Ps[w][l15 * 40 + nh * 16 + quad * 4 + 2] =
            pack2h(o[s][ni][2] * inv, o[s][ni][3] * inv);
      }
      __asm__ volatile("s_waitcnt lgkmcnt(0)" ::: "memory");
      uint4 x = *(const uint4*)&Ps[w][l15 * 40 + quad * 8];
      *(uint4*)(orow + p * 32 + quad * 8) = x;
      __asm__ volatile("s_waitcnt lgkmcnt(0)" ::: "memory");  // reads before reuse
    }
  }
}

// ---------------------------------------------------------------------- launch
extern "C" void kernel_launch(void* const* d_in, const int* in_sizes, int n_in,
                              void* d_out, int out_size, void* d_ws, size_t ws_size,
                              hipStream_t stream) {
  const float* x = (const float*)d_in[0];       // [4,2048,1024]
  const float* wqkv = (const float*)d_in[1];    // [3072,1024]
  const float* wo = (const float*)d_in[2];      // [1024,1024]
  float* out = (float*)d_out;                   // [4,2048,1024] fp32

  ushort* xh = (ushort*)d_ws;                          // 8192*1024
  ushort* wqkvh = xh + (size_t)8192 * 1024;            // 3072*1024
  ushort* woh = wqkvh + (size_t)3072 * 1024;           // 1024*1024
  ushort* qkvh = woh + (size_t)1024 * 1024;            // 8192*3072
  ushort* attnh = qkvh + (size_t)8192 * 3072;          // 8192*1024
  ushort* vtg = attnh + (size_t)8192 * 1024;           // 64*64*2048
  // total ws use: ~109 MB

  cast_f32_f16<<<8192, 256, 0, stream>>>(x, xh);
  cast_f32_f16<<<3072, 256, 0, stream>>>(wqkv, wqkvh);
  cast_f32_f16<<<1024, 256, 0, stream>>>(wo, woh);

  gemm_bt<1><<<dim3(24, 64), 256, 0, stream>>>(xh, wqkvh, qkvh, 8192, 3072, 1024);
  vtrans<<<dim3(32, 64), 256, 0, stream>>>(qkvh, vtg);
  attn_fused<<<dim3(1024), 256, 0, stream>>>(qkvh, vtg, attnh);
  gemm_bt<0><<<dim3(8, 64), 256, 0, stream>>>(attnh, woh, out, 8192, 1024, 1024);
}